// Round 8
// baseline (150.035 us; speedup 1.0000x reference)
//
#include <hip/hip_runtime.h>

#define NCODES 512
#define DIM 128
#define NROWS (64*2048)          // 131072
#define QN (NROWS*DIM)           // 16777216
#define TILE_ROWS 512            // rows per sweep block
#define HALFC 256                // codes per sweep block
#define NSWEEP (NROWS/TILE_ROWS*2) // 512 blocks: (row-tile, code-half)
#define OUT_ROWS 64
#define NOUT (NROWS/OUT_ROWS)    // 2048

typedef __attribute__((ext_vector_type(8))) short short8;
typedef __attribute__((ext_vector_type(4))) float f32x4;

__device__ __forceinline__ unsigned short f2bf(float f) {
  unsigned u = __builtin_bit_cast(unsigned, f);
  u += 0x7FFFu + ((u >> 16) & 1u);   // RNE
  return (unsigned short)(u >> 16);
}

#define GLOAD_LDS16(gp, lp) __builtin_amdgcn_global_load_lds( \
    (__attribute__((address_space(1))) void*)(gp), \
    (__attribute__((address_space(3))) void*)(lp), 16, 0, 0)

// ---------------- prep: bf16 codebook + per-code weights ----------------
__global__ void vq_prep(const float* __restrict__ emb, const float* __restrict__ scaling,
                        unsigned short* __restrict__ emb_bf,
                        float* __restrict__ wv, float* __restrict__ wse,
                        float* __restrict__ wrcp) {
  int k = blockIdx.x;
  int l = threadIdx.x; // 64 lanes
  float2 v = ((const float2*)(emb + k * DIM))[l];
  float ss = v.x * v.x + v.y * v.y;
#pragma unroll
  for (int m = 1; m < 64; m <<= 1) ss += __shfl_xor(ss, m);
  unsigned pack = (unsigned)f2bf(v.x) | ((unsigned)f2bf(v.y) << 16);
  ((unsigned*)emb_bf)[k * 64 + l] = pack;
  if (l == 0) {
    float hr = 40.0f + (float)k * (140.0f / 511.0f);
    float wt = 1.0f + scaling[k] * ((hr - 100.0f) * (1.0f / 70.0f));
    wv[k] = wt;
    wse[k] = wt * ss;        // w_k * ||e_k||^2
    wrcp[k] = 1.0f / wt;     // exact IEEE divide
  }
}

// ---------------- sweep: split-codes argmin, packed u32 candidates ----------
// 512 blocks x 1024 threads. Block (rt,h): rows rt*512..+512 vs codes
// h*256..+256. 64KB frag-ordered LDS half-codebook -> 2 blocks/CU, phases of
// co-resident blocks decorrelate (read under sweep). Winner packed as
// (dist_bits & ~0x1FF) | code: dist>=0 so u32 order == (dist, code) order ->
// min_u32 is argmin with tie->smaller-code, and combine across halves in the
// out kernel is a single min.
struct SweepSm {
  unsigned short frag[HALFC * DIM]; // 65536 B
  float w[HALFC];
  float wse[HALFC];
};

__global__ __launch_bounds__(1024, 8) void vq_sweep(
    const float* __restrict__ x,
    const unsigned short* __restrict__ emb_bf,
    const float* __restrict__ wv,
    const float* __restrict__ wse,
    unsigned* __restrict__ cand) {
  __shared__ SweepSm sm;
  const int tid = threadIdx.x;
  const int wave = tid >> 6, lane = tid & 63;
  const int g = lane >> 4, lr = lane & 15;
  const int rt = blockIdx.x >> 1;
  const int h = blockIdx.x & 1;
  const long rowbase = (long)rt * TILE_ROWS + wave * 32;

  // --- Issue x loads (registers) ---
  float4 xv[2][4][2];
#pragma unroll
  for (int rg = 0; rg < 2; rg++) {
    const float* xr = x + (rowbase + rg * 16 + lr) * DIM + g * 8;
#pragma unroll
    for (int c = 0; c < 4; c++) {
      xv[rg][c][0] = *(const float4*)(xr + c * 32);
      xv[rg][c][1] = *(const float4*)(xr + c * 32 + 4);
    }
  }

  // --- Stage half-codebook (64KB), fragment-ordered via source swizzle.
  {
    const uint4* src = (const uint4*)emb_bf;
#pragma unroll
    for (int i = 0; i < 4; i++) {
      int winst = wave * 4 + i;                  // 0..63
      int d = winst * 64 + lane;                 // dest 16B slot 0..4095
      int tl = d >> 8, c = (d >> 6) & 3, gg = (d >> 4) & 3, rr = d & 15;
      int s = (h * HALFC + tl * 16 + rr) * 16 + c * 4 + gg;  // row-major src
      GLOAD_LDS16(src + s, (char*)sm.frag + winst * 1024);
    }
    if (tid < HALFC) {
      sm.w[tid] = wv[h * HALFC + tid];
      sm.wse[tid] = wse[h * HALFC + tid];
    }
  }

  // --- Convert x to A fragments + row sumsq (overlaps staging latency).
  short8 a[2][4];
  float sr[2][4];
  {
    float srow[2];
#pragma unroll
    for (int rg = 0; rg < 2; rg++) {
      float ss = 0.f;
#pragma unroll
      for (int c = 0; c < 4; c++) {
        float4 v0 = xv[rg][c][0];
        float4 v1 = xv[rg][c][1];
        ss += v0.x * v0.x + v0.y * v0.y + v0.z * v0.z + v0.w * v0.w;
        ss += v1.x * v1.x + v1.y * v1.y + v1.z * v1.z + v1.w * v1.w;
        short8 av;
        av[0] = (short)f2bf(v0.x); av[1] = (short)f2bf(v0.y);
        av[2] = (short)f2bf(v0.z); av[3] = (short)f2bf(v0.w);
        av[4] = (short)f2bf(v1.x); av[5] = (short)f2bf(v1.y);
        av[6] = (short)f2bf(v1.z); av[7] = (short)f2bf(v1.w);
        a[rg][c] = av;
      }
      ss += __shfl_xor(ss, 16);
      ss += __shfl_xor(ss, 32);
      srow[rg] = ss;
    }
#pragma unroll
    for (int rg = 0; rg < 2; rg++)
#pragma unroll
      for (int r = 0; r < 4; r++)
        sr[rg][r] = __shfl(srow[rg], g * 4 + r);  // ||x||^2 of C-row 4g+r
  }
  __syncthreads();  // half-codebook staged; LDS read-only from here

  // --- Sweep 16 column tiles of 16 codes; running packed-min per lane.
  unsigned pmin[2][4];
#pragma unroll
  for (int rg = 0; rg < 2; rg++)
#pragma unroll
    for (int r = 0; r < 4; r++) pmin[rg][r] = 0xFFFFFFFFu;

  const short8* __restrict__ bbase = (const short8*)sm.frag + lane;
  for (int t = 0; t < 16; t++) {
    const int codeL = t * 16 + lr;        // local code (B col = lane&15)
    const unsigned codeG = h * HALFC + codeL;
    const float wt = sm.w[codeL];
    const float bb = sm.wse[codeL];
    const float m2w = -2.0f * wt;
    f32x4 acc0 = {0.f, 0.f, 0.f, 0.f};
    f32x4 acc1 = {0.f, 0.f, 0.f, 0.f};
#pragma unroll
    for (int c = 0; c < 4; c++) {
      short8 bf = bbase[(t * 4 + c) * 64];
      acc0 = __builtin_amdgcn_mfma_f32_16x16x32_bf16(a[0][c], bf, acc0, 0, 0, 0);
      acc1 = __builtin_amdgcn_mfma_f32_16x16x32_bf16(a[1][c], bf, acc1, 0, 0, 0);
    }
#pragma unroll
    for (int r = 0; r < 4; r++) {
      float v0 = fmaf(m2w, acc0[r], fmaf(wt, sr[0][r], bb));
      float v1 = fmaf(m2w, acc1[r], fmaf(wt, sr[1][r], bb));
      unsigned u0 = (__builtin_bit_cast(unsigned, v0) & 0xFFFFFE00u) | codeG;
      unsigned u1 = (__builtin_bit_cast(unsigned, v1) & 0xFFFFFE00u) | codeG;
      pmin[0][r] = min(pmin[0][r], u0);
      pmin[1][r] = min(pmin[1][r], u1);
    }
  }

  // --- Butterfly min across the 16 lanes of each group (packed: 1 min/step).
#pragma unroll
  for (int m = 1; m <= 8; m <<= 1) {
#pragma unroll
    for (int rg = 0; rg < 2; rg++)
#pragma unroll
      for (int r = 0; r < 4; r++) {
        unsigned o = (unsigned)__shfl_xor((int)pmin[rg][r], m);
        pmin[rg][r] = min(pmin[rg][r], o);
      }
  }

  // --- Emit candidates (one u32 per row per half).
  if (lr == 0) {
#pragma unroll
    for (int rg = 0; rg < 2; rg++)
#pragma unroll
      for (int r = 0; r < 4; r++)
        cand[(rowbase + rg * 16 + g * 4 + r) * 2 + h] = pmin[rg][r];
  }
}

// ---------------- out: combine halves, gather, store, loss partials --------
__global__ __launch_bounds__(256) void vq_out(
    const unsigned* __restrict__ cand,
    const float* __restrict__ emb32,
    const float* __restrict__ wrcp,
    float* __restrict__ out_q,
    float* __restrict__ out_idx,
    float* __restrict__ partials) {
  __shared__ int codes[OUT_ROWS];
  const int tid = threadIdx.x;
  const long rb = (long)blockIdx.x * OUT_ROWS;

  if (tid < OUT_ROWS) {  // exactly wave 0
    unsigned a = cand[(rb + tid) * 2];
    unsigned b = cand[(rb + tid) * 2 + 1];
    unsigned wn = min(a, b);           // global argmin (tie -> smaller code)
    int code = (int)(wn & 511u);
    codes[tid] = code;
    out_idx[rb + tid] = (float)code;
    float dist = __builtin_bit_cast(float, wn & 0xFFFFFE00u);
    float lc = dist * wrcp[code];
#pragma unroll
    for (int m = 1; m < 64; m <<= 1) lc += __shfl_xor(lc, m);
    if (tid == 0) partials[blockIdx.x] = lc;
  }
  __syncthreads();

  const uint4* __restrict__ esrc = (const uint4*)emb32;  // 32 uint4 per row
  uint4* __restrict__ outu = (uint4*)out_q + rb * 32;
#pragma unroll
  for (int it = 0; it < 8; it++) {
    int pos = it * 256 + tid;          // 0..2047
    int row = pos >> 5, col = pos & 31;
    outu[pos] = esrc[codes[row] * 32 + col];
  }
}

// ---------------- deterministic loss reduction ----------------
__global__ void vq_loss(const float* __restrict__ partials, float* __restrict__ out_loss) {
  __shared__ float red[16];
  const int t = threadIdx.x;
  float s = 0.f;
  for (int i = t; i < NOUT; i += 1024) s += partials[i];
#pragma unroll
  for (int m = 1; m < 64; m <<= 1) s += __shfl_xor(s, m);
  if ((t & 63) == 0) red[t >> 6] = s;
  __syncthreads();
  if (t == 0) {
    float tot = 0.f;
    for (int i = 0; i < 16; i++) tot += red[i];
    // loss = (1 + 0.6) * mean((q - x)^2) over all QN elements
    out_loss[0] = tot * (1.6f / (float)QN);
  }
}

extern "C" void kernel_launch(void* const* d_in, const int* in_sizes, int n_in,
                              void* d_out, int out_size, void* d_ws, size_t ws_size,
                              hipStream_t stream) {
  const float* x = (const float*)d_in[0];
  const float* emb = (const float*)d_in[1];
  const float* scaling = (const float*)d_in[2];

  float* out_q = (float*)d_out;
  float* out_loss = out_q + QN;
  float* out_idx = out_q + QN + 1;

  unsigned short* emb_bf = (unsigned short*)d_ws;                 // 128KB
  float* wv = (float*)((char*)d_ws + NCODES * DIM * 2);           // 2KB
  float* wse = wv + NCODES;                                       // 2KB
  float* wrcp = wse + NCODES;                                     // 2KB
  float* partials = wrcp + NCODES;                                // 8KB
  unsigned* cand = (unsigned*)(partials + NOUT);                  // 1MB

  vq_prep<<<NCODES, 64, 0, stream>>>(emb, scaling, emb_bf, wv, wse, wrcp);
  vq_sweep<<<NSWEEP, 1024, 0, stream>>>(x, emb_bf, wv, wse, cand);
  vq_out<<<NOUT, 256, 0, stream>>>(cand, emb, wrcp, out_q, out_idx, partials);
  vq_loss<<<1, 1024, 0, stream>>>(partials, out_loss);
}

// Round 9
// 71.507 us; speedup vs baseline: 2.0982x; 2.0982x over previous
//
#include <hip/hip_runtime.h>

#define NCODES 512
#define DIM 128
#define NROWS (64*2048)          // 131072
#define QN (NROWS*DIM)           // 16777216
#define TILE_ROWS 128            // rows per sweep block (4 waves x 32)
#define NTILES (NROWS/TILE_ROWS) // 1024
#define QC 128                   // codes per quarter
#define NQ 4
#define OUT_ROWS 64
#define NOUT (NROWS/OUT_ROWS)    // 2048

typedef __attribute__((ext_vector_type(8))) short short8;
typedef __attribute__((ext_vector_type(4))) float f32x4;

__device__ __forceinline__ unsigned short f2bf(float f) {
  unsigned u = __builtin_bit_cast(unsigned, f);
  u += 0x7FFFu + ((u >> 16) & 1u);   // RNE
  return (unsigned short)(u >> 16);
}

#define GLOAD_LDS16(gp, lp) __builtin_amdgcn_global_load_lds( \
    (__attribute__((address_space(1))) void*)(gp), \
    (__attribute__((address_space(3))) void*)(lp), 16, 0, 0)

// ---------------- prep: bf16 codebook + per-code weights ----------------
__global__ void vq_prep(const float* __restrict__ emb, const float* __restrict__ scaling,
                        unsigned short* __restrict__ emb_bf,
                        float* __restrict__ wv, float* __restrict__ wse,
                        float* __restrict__ wrcp) {
  int k = blockIdx.x;
  int l = threadIdx.x; // 64 lanes
  float2 v = ((const float2*)(emb + k * DIM))[l];
  float ss = v.x * v.x + v.y * v.y;
#pragma unroll
  for (int m = 1; m < 64; m <<= 1) ss += __shfl_xor(ss, m);
  unsigned pack = (unsigned)f2bf(v.x) | ((unsigned)f2bf(v.y) << 16);
  ((unsigned*)emb_bf)[k * 64 + l] = pack;
  if (l == 0) {
    float hr = 40.0f + (float)k * (140.0f / 511.0f);
    float wt = 1.0f + scaling[k] * ((hr - 100.0f) * (1.0f / 70.0f));
    wv[k] = wt;
    wse[k] = wt * ss;        // w_k * ||e_k||^2
    wrcp[k] = 1.0f / wt;     // exact IEEE divide
  }
}

// ---------------- sweep: quarter-codebook argmin, packed u32 candidates -----
// 4096 blocks x 256 threads. Block (tile, q): 128 rows vs codes q*128..+128.
// 33KB LDS -> 4 blocks/CU (launch_bounds(256,4), VGPR cap 128: no spills).
// XCD swizzle co-locates a tile's 4 quarters on one XCD so x re-reads hit L2:
// b = t_hi*32 + q*8 + t_lo  (b%8 == t_lo for all q).
// Winner packed (dist_bits & ~0x1FF) | code: dist>=0 -> u32 order == (dist,
// code) order -> min_u32 = argmin with tie->smaller code (validated R8).
struct SweepSm {
  unsigned short frag[QC * DIM];   // 32768 B, fragment-ordered
  float w[QC];
  float wse[QC];
};

__global__ __launch_bounds__(256, 4) void vq_sweep(
    const float* __restrict__ x,
    const unsigned short* __restrict__ emb_bf,
    const float* __restrict__ wv,
    const float* __restrict__ wse,
    unsigned* __restrict__ cand) {
  __shared__ SweepSm sm;
  const int tid = threadIdx.x;
  const int wave = tid >> 6, lane = tid & 63;
  const int g = lane >> 4, lr = lane & 15;
  const int b = blockIdx.x;
  const int tile = (b >> 5) * 8 + (b & 7);
  const int q = (b >> 3) & 3;
  const int qbase = q * QC;
  const long rowbase = (long)tile * TILE_ROWS + wave * 32;

  // --- Issue x loads (registers) ---
  float4 xv[2][4][2];
#pragma unroll
  for (int rg = 0; rg < 2; rg++) {
    const float* xr = x + (rowbase + rg * 16 + lr) * DIM + g * 8;
#pragma unroll
    for (int c = 0; c < 4; c++) {
      xv[rg][c][0] = *(const float4*)(xr + c * 32);
      xv[rg][c][1] = *(const float4*)(xr + c * 32 + 4);
    }
  }

  // --- Stage quarter-codebook (32KB), fragment-ordered via source swizzle.
  {
    const uint4* src = (const uint4*)emb_bf;
#pragma unroll
    for (int i = 0; i < 8; i++) {
      int winst = wave * 8 + i;                  // 0..31
      int d = winst * 64 + lane;                 // dest 16B slot 0..2047
      int tl = d >> 8, c = (d >> 6) & 3, gg = (d >> 4) & 3, rr = d & 15;
      int s = (qbase + tl * 16 + rr) * 16 + c * 4 + gg;  // row-major src slot
      GLOAD_LDS16(src + s, (char*)sm.frag + winst * 1024);
    }
    if (tid < QC) {
      sm.w[tid] = wv[qbase + tid];
      sm.wse[tid] = wse[qbase + tid];
    }
  }

  // --- Convert x to A fragments + row sumsq (overlaps staging latency).
  short8 a[2][4];
  float sr[2][4];
  {
    float srow[2];
#pragma unroll
    for (int rg = 0; rg < 2; rg++) {
      float ss = 0.f;
#pragma unroll
      for (int c = 0; c < 4; c++) {
        float4 v0 = xv[rg][c][0];
        float4 v1 = xv[rg][c][1];
        ss += v0.x * v0.x + v0.y * v0.y + v0.z * v0.z + v0.w * v0.w;
        ss += v1.x * v1.x + v1.y * v1.y + v1.z * v1.z + v1.w * v1.w;
        short8 av;
        av[0] = (short)f2bf(v0.x); av[1] = (short)f2bf(v0.y);
        av[2] = (short)f2bf(v0.z); av[3] = (short)f2bf(v0.w);
        av[4] = (short)f2bf(v1.x); av[5] = (short)f2bf(v1.y);
        av[6] = (short)f2bf(v1.z); av[7] = (short)f2bf(v1.w);
        a[rg][c] = av;
      }
      ss += __shfl_xor(ss, 16);
      ss += __shfl_xor(ss, 32);
      srow[rg] = ss;
    }
#pragma unroll
    for (int rg = 0; rg < 2; rg++)
#pragma unroll
      for (int r = 0; r < 4; r++)
        sr[rg][r] = __shfl(srow[rg], g * 4 + r);  // ||x||^2 of C-row 4g+r
  }
  __syncthreads();  // quarter staged; LDS read-only from here

  // --- Sweep 8 column tiles of 16 codes; running packed-min per lane.
  unsigned pmin[2][4];
#pragma unroll
  for (int rg = 0; rg < 2; rg++)
#pragma unroll
    for (int r = 0; r < 4; r++) pmin[rg][r] = 0xFFFFFFFFu;

  const short8* __restrict__ bbase = (const short8*)sm.frag + lane;
#pragma unroll
  for (int t = 0; t < 8; t++) {
    const int codeL = t * 16 + lr;
    const unsigned codeG = qbase + codeL;
    const float wt = sm.w[codeL];
    const float bb = sm.wse[codeL];
    const float m2w = -2.0f * wt;
    f32x4 acc0 = {0.f, 0.f, 0.f, 0.f};
    f32x4 acc1 = {0.f, 0.f, 0.f, 0.f};
#pragma unroll
    for (int c = 0; c < 4; c++) {
      short8 bf = bbase[(t * 4 + c) * 64];
      acc0 = __builtin_amdgcn_mfma_f32_16x16x32_bf16(a[0][c], bf, acc0, 0, 0, 0);
      acc1 = __builtin_amdgcn_mfma_f32_16x16x32_bf16(a[1][c], bf, acc1, 0, 0, 0);
    }
#pragma unroll
    for (int r = 0; r < 4; r++) {
      float v0 = fmaf(m2w, acc0[r], fmaf(wt, sr[0][r], bb));
      float v1 = fmaf(m2w, acc1[r], fmaf(wt, sr[1][r], bb));
      unsigned u0 = (__builtin_bit_cast(unsigned, v0) & 0xFFFFFE00u) | codeG;
      unsigned u1 = (__builtin_bit_cast(unsigned, v1) & 0xFFFFFE00u) | codeG;
      pmin[0][r] = min(pmin[0][r], u0);
      pmin[1][r] = min(pmin[1][r], u1);
    }
  }

  // --- Butterfly min across the 16 lanes of each group.
#pragma unroll
  for (int m = 1; m <= 8; m <<= 1) {
#pragma unroll
    for (int rg = 0; rg < 2; rg++)
#pragma unroll
      for (int r = 0; r < 4; r++) {
        unsigned o = (unsigned)__shfl_xor((int)pmin[rg][r], m);
        pmin[rg][r] = min(pmin[rg][r], o);
      }
  }

  // --- Emit candidates: one u32 per (row, quarter); uint4-per-row layout.
  if (lr == 0) {
#pragma unroll
    for (int rg = 0; rg < 2; rg++)
#pragma unroll
      for (int r = 0; r < 4; r++)
        cand[(rowbase + rg * 16 + g * 4 + r) * NQ + q] = pmin[rg][r];
  }
}

// ---------------- out: combine quarters, gather, store, loss partials ------
__global__ __launch_bounds__(256) void vq_out(
    const unsigned* __restrict__ cand,
    const float* __restrict__ emb32,
    const float* __restrict__ wrcp,
    float* __restrict__ out_q,
    float* __restrict__ out_idx,
    float* __restrict__ partials) {
  __shared__ int codes[OUT_ROWS];
  const int tid = threadIdx.x;
  const long rb = (long)blockIdx.x * OUT_ROWS;

  if (tid < OUT_ROWS) {  // exactly wave 0
    uint4 c4 = ((const uint4*)cand)[rb + tid];
    unsigned wn = min(min(c4.x, c4.y), min(c4.z, c4.w));
    int code = (int)(wn & 511u);
    codes[tid] = code;
    out_idx[rb + tid] = (float)code;
    float dist = __builtin_bit_cast(float, wn & 0xFFFFFE00u);
    float lc = dist * wrcp[code];
#pragma unroll
    for (int m = 1; m < 64; m <<= 1) lc += __shfl_xor(lc, m);
    if (tid == 0) partials[blockIdx.x] = lc;
  }
  __syncthreads();

  const uint4* __restrict__ esrc = (const uint4*)emb32;  // 32 uint4 per row
  uint4* __restrict__ outu = (uint4*)out_q + rb * 32;
#pragma unroll
  for (int it = 0; it < 8; it++) {
    int pos = it * 256 + tid;          // 0..2047
    int row = pos >> 5, col = pos & 31;
    outu[pos] = esrc[codes[row] * 32 + col];
  }
}

// ---------------- deterministic loss reduction ----------------
__global__ void vq_loss(const float* __restrict__ partials, float* __restrict__ out_loss) {
  __shared__ float red[16];
  const int t = threadIdx.x;
  float s = 0.f;
  for (int i = t; i < NOUT; i += 1024) s += partials[i];
#pragma unroll
  for (int m = 1; m < 64; m <<= 1) s += __shfl_xor(s, m);
  if ((t & 63) == 0) red[t >> 6] = s;
  __syncthreads();
  if (t == 0) {
    float tot = 0.f;
    for (int i = 0; i < 16; i++) tot += red[i];
    // loss = (1 + 0.6) * mean((q - x)^2) over all QN elements
    out_loss[0] = tot * (1.6f / (float)QN);
  }
}

extern "C" void kernel_launch(void* const* d_in, const int* in_sizes, int n_in,
                              void* d_out, int out_size, void* d_ws, size_t ws_size,
                              hipStream_t stream) {
  const float* x = (const float*)d_in[0];
  const float* emb = (const float*)d_in[1];
  const float* scaling = (const float*)d_in[2];

  float* out_q = (float*)d_out;
  float* out_loss = out_q + QN;
  float* out_idx = out_q + QN + 1;

  unsigned short* emb_bf = (unsigned short*)d_ws;                 // 128KB
  float* wv = (float*)((char*)d_ws + NCODES * DIM * 2);           // 2KB
  float* wse = wv + NCODES;                                       // 2KB
  float* wrcp = wse + NCODES;                                     // 2KB
  float* partials = wrcp + NCODES;                                // 8KB
  unsigned* cand = (unsigned*)(partials + NOUT);                  // 2MB (16B-aligned)

  vq_prep<<<NCODES, 64, 0, stream>>>(emb, scaling, emb_bf, wv, wse, wrcp);
  vq_sweep<<<NTILES * NQ, 256, 0, stream>>>(x, emb_bf, wv, wse, cand);
  vq_out<<<NOUT, 256, 0, stream>>>(cand, emb, wrcp, out_q, out_idx, partials);
  vq_loss<<<1, 1024, 0, stream>>>(partials, out_loss);
}

// Round 10
// 53.590 us; speedup vs baseline: 2.7997x; 1.3343x over previous
//
#include <hip/hip_runtime.h>

#define NCODES 512
#define DIM 128
#define NROWS (64*2048)          // 131072
#define QN (NROWS*DIM)           // 16777216
#define TILE_ROWS 256            // rows per sweep block (8 waves x 32)
#define NTILES (NROWS/TILE_ROWS) // 512
#define HALFC 256                // codes per half
#define OUT_ROWS 64
#define NOUT (NROWS/OUT_ROWS)    // 2048

typedef __attribute__((ext_vector_type(8))) short short8;
typedef __attribute__((ext_vector_type(4))) float f32x4;

__device__ __forceinline__ unsigned short f2bf(float f) {
  unsigned u = __builtin_bit_cast(unsigned, f);
  u += 0x7FFFu + ((u >> 16) & 1u);   // RNE
  return (unsigned short)(u >> 16);
}

#define GLOAD_LDS16(gp, lp) __builtin_amdgcn_global_load_lds( \
    (__attribute__((address_space(1))) void*)(gp), \
    (__attribute__((address_space(3))) void*)(lp), 16, 0, 0)

// ---------------- prep: bf16 codebook + per-code weights ----------------
__global__ void vq_prep(const float* __restrict__ emb, const float* __restrict__ scaling,
                        unsigned short* __restrict__ emb_bf,
                        float* __restrict__ wv, float* __restrict__ wse,
                        float* __restrict__ wrcp) {
  int k = blockIdx.x;
  int l = threadIdx.x; // 64 lanes
  float2 v = ((const float2*)(emb + k * DIM))[l];
  float ss = v.x * v.x + v.y * v.y;
#pragma unroll
  for (int m = 1; m < 64; m <<= 1) ss += __shfl_xor(ss, m);
  unsigned pack = (unsigned)f2bf(v.x) | ((unsigned)f2bf(v.y) << 16);
  ((unsigned*)emb_bf)[k * 64 + l] = pack;
  if (l == 0) {
    float hr = 40.0f + (float)k * (140.0f / 511.0f);
    float wt = 1.0f + scaling[k] * ((hr - 100.0f) * (1.0f / 70.0f));
    wv[k] = wt;
    wse[k] = wt * ss;        // w_k * ||e_k||^2
    wrcp[k] = 1.0f / wt;     // exact IEEE divide
  }
}

// ---------------- sweep: half-codebook argmin, packed u32 candidates --------
// 1024 blocks x 512 threads (8 waves x 32 rows). Block (tile,h): 256 rows vs
// codes h*256..+256. LDS 67.6KB -> 2 blocks/CU (launch_bounds(512,4): VGPR
// cap 128, measured need ~60), 4 block-rounds/CU -> co-resident independent
// blocks decorrelate phases (one reads x while the other sweeps LDS/MFMA).
// XCD swizzle co-locates both halves of a tile (b%8 invariant in h) so the
// 2x x re-read stays in L2 (R9-confirmed: FETCH stays ~33MB).
// Winner packed (dist_bits & ~0x1FF) | code: dist>=0 -> u32 order == (dist,
// code) -> min_u32 = argmin, tie -> smaller code (R8/R9-validated).
struct SweepSm {
  unsigned short frag[HALFC * DIM]; // 65536 B, fragment-ordered
  float w[HALFC];
  float wse[HALFC];
};

__global__ __launch_bounds__(512, 4) void vq_sweep(
    const float* __restrict__ x,
    const unsigned short* __restrict__ emb_bf,
    const float* __restrict__ wv,
    const float* __restrict__ wse,
    unsigned* __restrict__ cand) {
  __shared__ SweepSm sm;
  const int tid = threadIdx.x;
  const int wave = tid >> 6, lane = tid & 63;
  const int g = lane >> 4, lr = lane & 15;
  const int b = blockIdx.x;
  const int tile = (b >> 4) * 8 + (b & 7);   // [0,512)
  const int h = (b >> 3) & 1;
  const int hbase = h * HALFC;
  const long rowbase = (long)tile * TILE_ROWS + wave * 32;

  // --- Issue x loads (registers) ---
  float4 xv[2][4][2];
#pragma unroll
  for (int rg = 0; rg < 2; rg++) {
    const float* xr = x + (rowbase + rg * 16 + lr) * DIM + g * 8;
#pragma unroll
    for (int c = 0; c < 4; c++) {
      xv[rg][c][0] = *(const float4*)(xr + c * 32);
      xv[rg][c][1] = *(const float4*)(xr + c * 32 + 4);
    }
  }

  // --- Stage half-codebook (64KB), fragment-ordered via source swizzle.
  {
    const uint4* src = (const uint4*)emb_bf;
#pragma unroll
    for (int i = 0; i < 8; i++) {
      int winst = wave * 8 + i;                  // 0..63
      int d = winst * 64 + lane;                 // dest 16B slot 0..4095
      int tl = d >> 8, c = (d >> 6) & 3, gg = (d >> 4) & 3, rr = d & 15;
      int s = (hbase + tl * 16 + rr) * 16 + c * 4 + gg;  // row-major src slot
      GLOAD_LDS16(src + s, (char*)sm.frag + winst * 1024);
    }
    if (tid < HALFC) {
      sm.w[tid] = wv[hbase + tid];
      sm.wse[tid] = wse[hbase + tid];
    }
  }

  // --- Convert x to A fragments + row sumsq (overlaps staging latency).
  short8 a[2][4];
  float sr[2][4];
  {
    float srow[2];
#pragma unroll
    for (int rg = 0; rg < 2; rg++) {
      float ss = 0.f;
#pragma unroll
      for (int c = 0; c < 4; c++) {
        float4 v0 = xv[rg][c][0];
        float4 v1 = xv[rg][c][1];
        ss += v0.x * v0.x + v0.y * v0.y + v0.z * v0.z + v0.w * v0.w;
        ss += v1.x * v1.x + v1.y * v1.y + v1.z * v1.z + v1.w * v1.w;
        short8 av;
        av[0] = (short)f2bf(v0.x); av[1] = (short)f2bf(v0.y);
        av[2] = (short)f2bf(v0.z); av[3] = (short)f2bf(v0.w);
        av[4] = (short)f2bf(v1.x); av[5] = (short)f2bf(v1.y);
        av[6] = (short)f2bf(v1.z); av[7] = (short)f2bf(v1.w);
        a[rg][c] = av;
      }
      ss += __shfl_xor(ss, 16);
      ss += __shfl_xor(ss, 32);
      srow[rg] = ss;
    }
#pragma unroll
    for (int rg = 0; rg < 2; rg++)
#pragma unroll
      for (int r = 0; r < 4; r++)
        sr[rg][r] = __shfl(srow[rg], g * 4 + r);  // ||x||^2 of C-row 4g+r
  }
  __syncthreads();  // half staged; LDS read-only from here

  // --- Sweep 16 column tiles of 16 codes; running packed-min per lane.
  unsigned pmin[2][4];
#pragma unroll
  for (int rg = 0; rg < 2; rg++)
#pragma unroll
    for (int r = 0; r < 4; r++) pmin[rg][r] = 0xFFFFFFFFu;

  const short8* __restrict__ bbase = (const short8*)sm.frag + lane;
  for (int t = 0; t < 16; t++) {
    const int codeL = t * 16 + lr;
    const unsigned codeG = hbase + codeL;
    const float wt = sm.w[codeL];
    const float bb = sm.wse[codeL];
    const float m2w = -2.0f * wt;
    f32x4 acc0 = {0.f, 0.f, 0.f, 0.f};
    f32x4 acc1 = {0.f, 0.f, 0.f, 0.f};
#pragma unroll
    for (int c = 0; c < 4; c++) {
      short8 bf = bbase[(t * 4 + c) * 64];
      acc0 = __builtin_amdgcn_mfma_f32_16x16x32_bf16(a[0][c], bf, acc0, 0, 0, 0);
      acc1 = __builtin_amdgcn_mfma_f32_16x16x32_bf16(a[1][c], bf, acc1, 0, 0, 0);
    }
#pragma unroll
    for (int r = 0; r < 4; r++) {
      float v0 = fmaf(m2w, acc0[r], fmaf(wt, sr[0][r], bb));
      float v1 = fmaf(m2w, acc1[r], fmaf(wt, sr[1][r], bb));
      unsigned u0 = (__builtin_bit_cast(unsigned, v0) & 0xFFFFFE00u) | codeG;
      unsigned u1 = (__builtin_bit_cast(unsigned, v1) & 0xFFFFFE00u) | codeG;
      pmin[0][r] = min(pmin[0][r], u0);
      pmin[1][r] = min(pmin[1][r], u1);
    }
  }

  // --- Butterfly min across the 16 lanes of each group.
#pragma unroll
  for (int m = 1; m <= 8; m <<= 1) {
#pragma unroll
    for (int rg = 0; rg < 2; rg++)
#pragma unroll
      for (int r = 0; r < 4; r++) {
        unsigned o = (unsigned)__shfl_xor((int)pmin[rg][r], m);
        pmin[rg][r] = min(pmin[rg][r], o);
      }
  }

  // --- Emit candidates: one u32 per (row, half); uint2-per-row layout.
  if (lr == 0) {
#pragma unroll
    for (int rg = 0; rg < 2; rg++)
#pragma unroll
      for (int r = 0; r < 4; r++)
        cand[(rowbase + rg * 16 + g * 4 + r) * 2 + h] = pmin[rg][r];
  }
}

// ---------------- out: combine halves, gather, store, loss partials --------
__global__ __launch_bounds__(256) void vq_out(
    const unsigned* __restrict__ cand,
    const float* __restrict__ emb32,
    const float* __restrict__ wrcp,
    float* __restrict__ out_q,
    float* __restrict__ out_idx,
    float* __restrict__ partials) {
  __shared__ int codes[OUT_ROWS];
  const int tid = threadIdx.x;
  const long rb = (long)blockIdx.x * OUT_ROWS;

  if (tid < OUT_ROWS) {  // exactly wave 0
    uint2 c2 = ((const uint2*)cand)[rb + tid];
    unsigned wn = min(c2.x, c2.y);     // global argmin (tie -> smaller code)
    int code = (int)(wn & 511u);
    codes[tid] = code;
    out_idx[rb + tid] = (float)code;
    float dist = __builtin_bit_cast(float, wn & 0xFFFFFE00u);
    float lc = dist * wrcp[code];
#pragma unroll
    for (int m = 1; m < 64; m <<= 1) lc += __shfl_xor(lc, m);
    if (tid == 0) partials[blockIdx.x] = lc;
  }
  __syncthreads();

  const uint4* __restrict__ esrc = (const uint4*)emb32;  // 32 uint4 per row
  uint4* __restrict__ outu = (uint4*)out_q + rb * 32;
#pragma unroll
  for (int it = 0; it < 8; it++) {
    int pos = it * 256 + tid;          // 0..2047
    int row = pos >> 5, col = pos & 31;
    outu[pos] = esrc[codes[row] * 32 + col];
  }
}

// ---------------- deterministic loss reduction ----------------
__global__ void vq_loss(const float* __restrict__ partials, float* __restrict__ out_loss) {
  __shared__ float red[16];
  const int t = threadIdx.x;
  float s = 0.f;
  for (int i = t; i < NOUT; i += 1024) s += partials[i];
#pragma unroll
  for (int m = 1; m < 64; m <<= 1) s += __shfl_xor(s, m);
  if ((t & 63) == 0) red[t >> 6] = s;
  __syncthreads();
  if (t == 0) {
    float tot = 0.f;
    for (int i = 0; i < 16; i++) tot += red[i];
    // loss = (1 + 0.6) * mean((q - x)^2) over all QN elements
    out_loss[0] = tot * (1.6f / (float)QN);
  }
}

extern "C" void kernel_launch(void* const* d_in, const int* in_sizes, int n_in,
                              void* d_out, int out_size, void* d_ws, size_t ws_size,
                              hipStream_t stream) {
  const float* x = (const float*)d_in[0];
  const float* emb = (const float*)d_in[1];
  const float* scaling = (const float*)d_in[2];

  float* out_q = (float*)d_out;
  float* out_loss = out_q + QN;
  float* out_idx = out_q + QN + 1;

  unsigned short* emb_bf = (unsigned short*)d_ws;                 // 128KB
  float* wv = (float*)((char*)d_ws + NCODES * DIM * 2);           // 2KB
  float* wse = wv + NCODES;                                       // 2KB
  float* wrcp = wse + NCODES;                                     // 2KB
  float* partials = wrcp + NCODES;                                // 8KB
  unsigned* cand = (unsigned*)(partials + NOUT);                  // 1MB (8B-aligned)

  vq_prep<<<NCODES, 64, 0, stream>>>(emb, scaling, emb_bf, wv, wse, wrcp);
  vq_sweep<<<NTILES * 2, 512, 0, stream>>>(x, emb_bf, wv, wse, cand);
  vq_out<<<NOUT, 256, 0, stream>>>(cand, emb, wrcp, out_q, out_idx, partials);
  vq_loss<<<1, 1024, 0, stream>>>(partials, out_loss);
}

// Round 11
// 51.824 us; speedup vs baseline: 2.8951x; 1.0341x over previous
//
#include <hip/hip_runtime.h>

#define NCODES 512
#define DIM 128
#define NROWS (64*2048)          // 131072
#define QN (NROWS*DIM)           // 16777216
#define BLK_ROWS 512
#define NBLOCKS (NROWS/BLK_ROWS) // 256
#define NWAVES 16                // 1024 threads, 32 rows/wave

typedef __attribute__((ext_vector_type(8))) short short8;
typedef __attribute__((ext_vector_type(4))) float f32x4;

__device__ __forceinline__ unsigned short f2bf(float f) {
  unsigned u = __builtin_bit_cast(unsigned, f);
  u += 0x7FFFu + ((u >> 16) & 1u);   // RNE
  return (unsigned short)(u >> 16);
}

#define GLOAD_LDS16(gp, lp) __builtin_amdgcn_global_load_lds( \
    (__attribute__((address_space(1))) void*)(gp), \
    (__attribute__((address_space(3))) void*)(lp), 16, 0, 0)

// ---------------- prep: bf16 codebook + per-code weights ----------------
__global__ void vq_prep(const float* __restrict__ emb, const float* __restrict__ scaling,
                        unsigned short* __restrict__ emb_bf,
                        float* __restrict__ wv, float* __restrict__ wse,
                        float* __restrict__ wrcp) {
  int k = blockIdx.x;
  int l = threadIdx.x; // 64 lanes
  float2 v = ((const float2*)(emb + k * DIM))[l];
  float ss = v.x * v.x + v.y * v.y;
#pragma unroll
  for (int m = 1; m < 64; m <<= 1) ss += __shfl_xor(ss, m);
  unsigned pack = (unsigned)f2bf(v.x) | ((unsigned)f2bf(v.y) << 16);
  ((unsigned*)emb_bf)[k * 64 + l] = pack;
  if (l == 0) {
    float hr = 40.0f + (float)k * (140.0f / 511.0f);
    float wt = 1.0f + scaling[k] * ((hr - 100.0f) * (1.0f / 70.0f));
    wv[k] = wt;
    wse[k] = wt * ss;        // w_k * ||e_k||^2
    wrcp[k] = 1.0f / wt;     // exact IEEE divide
  }
}

// ---------------- main ----------------
// R7 skeleton (best measured): 256 blocks x 1024 threads, full codebook staged
// once fragment-ordered (conflict-free), ONE mid barrier, wave-owned stores.
// R11 deltas: unroll-2 sweep (2 t-iters of independent MFMA/ds in flight),
// batched store-gather (2 rounds of 8 outstanding uint4 loads), loss via
// per-block LDS reduce + single atomicAdd (drops the vq_loss kernel).
struct SmemT {
  unsigned short frag[NCODES * DIM]; // 131072 B
  float w[NCODES];
  float wse[NCODES];
  float wrcp[NCODES];
  float lossp[NWAVES];
};

__global__ __launch_bounds__(1024, 4) void vq_main(
    const float* __restrict__ x,
    const float* __restrict__ emb32,
    const unsigned short* __restrict__ emb_bf,
    const float* __restrict__ wv,
    const float* __restrict__ wse,
    const float* __restrict__ wrcp,
    float* __restrict__ out_q,
    float* __restrict__ out_idx,
    float* __restrict__ out_loss) {
  __shared__ SmemT sm;
  const int tid = threadIdx.x;
  const int wave = tid >> 6, lane = tid & 63;
  const int g = lane >> 4, lr = lane & 15;
  const long rowbase = (long)blockIdx.x * BLK_ROWS + wave * 32;

  // --- Issue x loads (registers) ---
  float4 xv[2][4][2];
#pragma unroll
  for (int rg = 0; rg < 2; rg++) {
    const float* xr = x + (rowbase + rg * 16 + lr) * DIM + g * 8;
#pragma unroll
    for (int c = 0; c < 4; c++) {
      xv[rg][c][0] = *(const float4*)(xr + c * 32);
      xv[rg][c][1] = *(const float4*)(xr + c * 32 + 4);
    }
  }

  // --- Issue codebook staging: global_load_lds, frag-order via source swizzle.
  {
    const uint4* src = (const uint4*)emb_bf;
#pragma unroll
    for (int i = 0; i < 8; i++) {
      int winst = wave * 8 + i;
      int d = winst * 64 + lane;                 // dest 16B slot 0..8191
      int t = d >> 8, c = (d >> 6) & 3, gg = (d >> 4) & 3, rr = d & 15;
      int s = (t * 16 + rr) * 16 + c * 4 + gg;   // source slot (row-major)
      GLOAD_LDS16(src + s, (char*)sm.frag + winst * 1024);
    }
    if (tid < NCODES) {
      sm.w[tid] = wv[tid];
      sm.wse[tid] = wse[tid];
      sm.wrcp[tid] = wrcp[tid];
    }
  }

  // --- Convert x to A fragments + row sumsq (overlaps staging latency).
  short8 a[2][4];
  float sr[2][4];
  {
    float srow[2];
#pragma unroll
    for (int rg = 0; rg < 2; rg++) {
      float ss = 0.f;
#pragma unroll
      for (int c = 0; c < 4; c++) {
        float4 v0 = xv[rg][c][0];
        float4 v1 = xv[rg][c][1];
        ss += v0.x * v0.x + v0.y * v0.y + v0.z * v0.z + v0.w * v0.w;
        ss += v1.x * v1.x + v1.y * v1.y + v1.z * v1.z + v1.w * v1.w;
        short8 av;
        av[0] = (short)f2bf(v0.x); av[1] = (short)f2bf(v0.y);
        av[2] = (short)f2bf(v0.z); av[3] = (short)f2bf(v0.w);
        av[4] = (short)f2bf(v1.x); av[5] = (short)f2bf(v1.y);
        av[6] = (short)f2bf(v1.z); av[7] = (short)f2bf(v1.w);
        a[rg][c] = av;
      }
      ss += __shfl_xor(ss, 16);
      ss += __shfl_xor(ss, 32);
      srow[rg] = ss;
    }
#pragma unroll
    for (int rg = 0; rg < 2; rg++)
#pragma unroll
      for (int r = 0; r < 4; r++)
        sr[rg][r] = __shfl(srow[rg], g * 4 + r);  // ||x||^2 of C-row 4g+r
  }
  __syncthreads();  // codebook staged; LDS read-only until loss phase

  // --- Sweep 32 column tiles of 16 codes; running weighted-argmin per lane.
  // unroll 2: consecutive t-iters are independent (fresh accs) -> 2x MFMA and
  // ds_read in flight hides LDS/MFMA latency.
  float vmin[2][4];
  int imin[2][4];
#pragma unroll
  for (int rg = 0; rg < 2; rg++)
#pragma unroll
    for (int r = 0; r < 4; r++) { vmin[rg][r] = 3.0e38f; imin[rg][r] = 0; }

  const short8* __restrict__ bbase = (const short8*)sm.frag + lane;
#pragma unroll 2
  for (int t = 0; t < 32; t++) {
    const int code = t * 16 + lr;         // B col = lane&15
    const float wt = sm.w[code];
    const float bb = sm.wse[code];
    const float m2w = -2.0f * wt;
    f32x4 acc0 = {0.f, 0.f, 0.f, 0.f};
    f32x4 acc1 = {0.f, 0.f, 0.f, 0.f};
#pragma unroll
    for (int c = 0; c < 4; c++) {
      short8 bf = bbase[(t * 4 + c) * 64];
      acc0 = __builtin_amdgcn_mfma_f32_16x16x32_bf16(a[0][c], bf, acc0, 0, 0, 0);
      acc1 = __builtin_amdgcn_mfma_f32_16x16x32_bf16(a[1][c], bf, acc1, 0, 0, 0);
    }
#pragma unroll
    for (int r = 0; r < 4; r++) {
      float v0 = fmaf(m2w, acc0[r], fmaf(wt, sr[0][r], bb));
      float v1 = fmaf(m2w, acc1[r], fmaf(wt, sr[1][r], bb));
      if (v0 < vmin[0][r]) { vmin[0][r] = v0; imin[0][r] = code; }
      if (v1 < vmin[1][r]) { vmin[1][r] = v1; imin[1][r] = code; }
    }
  }

  // --- Butterfly min-reduce across 16 lanes (tie -> smaller index).
#pragma unroll
  for (int m = 1; m <= 8; m <<= 1) {
#pragma unroll
    for (int rg = 0; rg < 2; rg++)
#pragma unroll
      for (int r = 0; r < 4; r++) {
        float ov = __shfl_xor(vmin[rg][r], m);
        int oi = __shfl_xor(imin[rg][r], m);
        if (ov < vmin[rg][r] || (ov == vmin[rg][r] && oi < imin[rg][r])) {
          vmin[rg][r] = ov; imin[rg][r] = oi;
        }
      }
  }

  // --- Winner processing: indices out, per-wave loss partial to LDS.
  {
    float l0 = 0.f;
#pragma unroll
    for (int rg = 0; rg < 2; rg++)
#pragma unroll
      for (int r = 0; r < 4; r++) {
        int ci = imin[rg][r];
        l0 = fmaf(vmin[rg][r], sm.wrcp[ci], l0);
        if (lr == 0) out_idx[rowbase + rg * 16 + g * 4 + r] = (float)ci;
      }
    // Group values identical across 16 lanes; the two xors add one lane from
    // each other group -> exact sum over the wave's 32 rows.
    l0 += __shfl_xor(l0, 16);
    l0 += __shfl_xor(l0, 32);
    if (lane == 0) sm.lossp[wave] = l0;
  }

  // --- Wave-owned store: 32 rows x 128 f32. Codes from registers via
  // compile-time shfls; gather batched 8-deep to amortize L2 latency.
  {
    const uint4* __restrict__ esrc = (const uint4*)emb32;   // 32 uint4/row
    uint4* __restrict__ outu = (uint4*)out_q + rowbase * 32;
    const int col = lane & 31;
    const int hi = lane >> 5;               // 0: row 2it, 1: row 2it+1
    int scode[16];
#pragma unroll
    for (int it = 0; it < 16; it++) {
      const int row0 = 2 * it;              // compile-time
      const int rg = row0 >> 4;
      const int gn = (row0 >> 2) & 3;
      const int r0 = row0 & 3;              // even
      int c0 = __shfl(imin[rg][r0], gn * 16);
      int c1 = __shfl(imin[rg][r0 + 1], gn * 16);
      scode[it] = hi ? c1 : c0;
    }
#pragma unroll
    for (int half = 0; half < 2; half++) {
      uint4 vbuf[8];
#pragma unroll
      for (int j = 0; j < 8; j++)
        vbuf[j] = esrc[scode[half * 8 + j] * 32 + col];
#pragma unroll
      for (int j = 0; j < 8; j++)
        outu[(half * 8 + j) * 64 + lane] = vbuf[j];
    }
  }

  // --- Per-block loss reduce + one atomic (256 atomics total, order-free sum
  // variance ~1e-7 << 3.2e-2 threshold).
  __syncthreads();
  if (wave == 0 && lane < NWAVES) {
    float s = sm.lossp[lane];
#pragma unroll
    for (int m = 1; m < NWAVES; m <<= 1) s += __shfl_xor(s, m);
    if (lane == 0) atomicAdd(out_loss, s * (1.6f / (float)QN));
  }
}

extern "C" void kernel_launch(void* const* d_in, const int* in_sizes, int n_in,
                              void* d_out, int out_size, void* d_ws, size_t ws_size,
                              hipStream_t stream) {
  const float* x = (const float*)d_in[0];
  const float* emb = (const float*)d_in[1];
  const float* scaling = (const float*)d_in[2];

  float* out_q = (float*)d_out;
  float* out_loss = out_q + QN;
  float* out_idx = out_q + QN + 1;

  unsigned short* emb_bf = (unsigned short*)d_ws;
  float* wv = (float*)((char*)d_ws + NCODES * DIM * 2);
  float* wse = wv + NCODES;
  float* wrcp = wse + NCODES;

  hipMemsetAsync(out_loss, 0, sizeof(float), stream);
  vq_prep<<<NCODES, 64, 0, stream>>>(emb, scaling, emb_bf, wv, wse, wrcp);
  vq_main<<<NBLOCKS, 1024, 0, stream>>>(x, emb, emb_bf, wv, wse, wrcp,
                                        out_q, out_idx, out_loss);
}

// Round 12
// 49.265 us; speedup vs baseline: 3.0454x; 1.0519x over previous
//
#include <hip/hip_runtime.h>

#define NCODES 512
#define DIM 128
#define NROWS (64*2048)          // 131072
#define QN (NROWS*DIM)           // 16777216
#define BLK_ROWS 512
#define NBLOCKS (NROWS/BLK_ROWS) // 256
#define NWAVES 16                // 1024 threads, 32 rows/wave

typedef __attribute__((ext_vector_type(8))) short short8;
typedef __attribute__((ext_vector_type(4))) float f32x4;

__device__ __forceinline__ unsigned short f2bf(float f) {
  unsigned u = __builtin_bit_cast(unsigned, f);
  u += 0x7FFFu + ((u >> 16) & 1u);   // RNE
  return (unsigned short)(u >> 16);
}

#define GLOAD_LDS16(gp, lp) __builtin_amdgcn_global_load_lds( \
    (__attribute__((address_space(1))) void*)(gp), \
    (__attribute__((address_space(3))) void*)(lp), 16, 0, 0)

// ---------------- prep: bf16 codebook + per-code weights ----------------
__global__ void vq_prep(const float* __restrict__ emb, const float* __restrict__ scaling,
                        unsigned short* __restrict__ emb_bf,
                        float* __restrict__ wv, float* __restrict__ wse,
                        float* __restrict__ wrcp) {
  int k = blockIdx.x;
  int l = threadIdx.x; // 64 lanes
  float2 v = ((const float2*)(emb + k * DIM))[l];
  float ss = v.x * v.x + v.y * v.y;
#pragma unroll
  for (int m = 1; m < 64; m <<= 1) ss += __shfl_xor(ss, m);
  unsigned pack = (unsigned)f2bf(v.x) | ((unsigned)f2bf(v.y) << 16);
  ((unsigned*)emb_bf)[k * 64 + l] = pack;
  if (l == 0) {
    float hr = 40.0f + (float)k * (140.0f / 511.0f);
    float wt = 1.0f + scaling[k] * ((hr - 100.0f) * (1.0f / 70.0f));
    wv[k] = wt;
    wse[k] = wt * ss;        // w_k * ||e_k||^2
    wrcp[k] = 1.0f / wt;     // exact IEEE divide
  }
}

// ---------------- main ----------------
// R7/R11 skeleton: 256 blocks x 1024 threads, full codebook staged once
// fragment-ordered (conflict-free), ONE mid barrier, wave-owned stores.
// R12: packed-u32 argmin (dist_bits&~0x1FF | code; dist>=0 -> u32 order ==
// (dist,code) order -> min = argmin, tie->smaller code; validated R8-R10),
// T14 store (gathers issued before loss/idx bookkeeping, written after),
// loss via per-block reduce + one atomicAdd.
struct SmemT {
  unsigned short frag[NCODES * DIM]; // 131072 B
  float w[NCODES];
  float wse[NCODES];
  float wrcp[NCODES];
  float lossp[NWAVES];
};

__global__ __launch_bounds__(1024, 4) void vq_main(
    const float* __restrict__ x,
    const float* __restrict__ emb32,
    const unsigned short* __restrict__ emb_bf,
    const float* __restrict__ wv,
    const float* __restrict__ wse,
    const float* __restrict__ wrcp,
    float* __restrict__ out_q,
    float* __restrict__ out_idx,
    float* __restrict__ out_loss) {
  __shared__ SmemT sm;
  const int tid = threadIdx.x;
  const int wave = tid >> 6, lane = tid & 63;
  const int g = lane >> 4, lr = lane & 15;
  const long rowbase = (long)blockIdx.x * BLK_ROWS + wave * 32;

  // --- Issue x loads (registers) ---
  float4 xv[2][4][2];
#pragma unroll
  for (int rg = 0; rg < 2; rg++) {
    const float* xr = x + (rowbase + rg * 16 + lr) * DIM + g * 8;
#pragma unroll
    for (int c = 0; c < 4; c++) {
      xv[rg][c][0] = *(const float4*)(xr + c * 32);
      xv[rg][c][1] = *(const float4*)(xr + c * 32 + 4);
    }
  }

  // --- Issue codebook staging: global_load_lds, frag-order via source swizzle.
  {
    const uint4* src = (const uint4*)emb_bf;
#pragma unroll
    for (int i = 0; i < 8; i++) {
      int winst = wave * 8 + i;
      int d = winst * 64 + lane;                 // dest 16B slot 0..8191
      int t = d >> 8, c = (d >> 6) & 3, gg = (d >> 4) & 3, rr = d & 15;
      int s = (t * 16 + rr) * 16 + c * 4 + gg;   // source slot (row-major)
      GLOAD_LDS16(src + s, (char*)sm.frag + winst * 1024);
    }
    if (tid < NCODES) {
      sm.w[tid] = wv[tid];
      sm.wse[tid] = wse[tid];
      sm.wrcp[tid] = wrcp[tid];
    }
  }

  // --- Convert x to A fragments + row sumsq (overlaps staging latency).
  short8 a[2][4];
  float sr[2][4];
  {
    float srow[2];
#pragma unroll
    for (int rg = 0; rg < 2; rg++) {
      float ss = 0.f;
#pragma unroll
      for (int c = 0; c < 4; c++) {
        float4 v0 = xv[rg][c][0];
        float4 v1 = xv[rg][c][1];
        ss += v0.x * v0.x + v0.y * v0.y + v0.z * v0.z + v0.w * v0.w;
        ss += v1.x * v1.x + v1.y * v1.y + v1.z * v1.z + v1.w * v1.w;
        short8 av;
        av[0] = (short)f2bf(v0.x); av[1] = (short)f2bf(v0.y);
        av[2] = (short)f2bf(v0.z); av[3] = (short)f2bf(v0.w);
        av[4] = (short)f2bf(v1.x); av[5] = (short)f2bf(v1.y);
        av[6] = (short)f2bf(v1.z); av[7] = (short)f2bf(v1.w);
        a[rg][c] = av;
      }
      ss += __shfl_xor(ss, 16);
      ss += __shfl_xor(ss, 32);
      srow[rg] = ss;
    }
#pragma unroll
    for (int rg = 0; rg < 2; rg++)
#pragma unroll
      for (int r = 0; r < 4; r++)
        sr[rg][r] = __shfl(srow[rg], g * 4 + r);  // ||x||^2 of C-row 4g+r
  }
  __syncthreads();  // codebook staged; LDS read-only until loss phase

  // --- Sweep 32 column tiles of 16 codes; running packed-min per lane.
  unsigned pmin[2][4];
#pragma unroll
  for (int rg = 0; rg < 2; rg++)
#pragma unroll
    for (int r = 0; r < 4; r++) pmin[rg][r] = 0xFFFFFFFFu;

  const short8* __restrict__ bbase = (const short8*)sm.frag + lane;
#pragma unroll 2
  for (int t = 0; t < 32; t++) {
    const unsigned code = t * 16 + lr;    // B col = lane&15
    const float wt = sm.w[code];
    const float bb = sm.wse[code];
    const float m2w = -2.0f * wt;
    f32x4 acc0 = {0.f, 0.f, 0.f, 0.f};
    f32x4 acc1 = {0.f, 0.f, 0.f, 0.f};
#pragma unroll
    for (int c = 0; c < 4; c++) {
      short8 bf = bbase[(t * 4 + c) * 64];
      acc0 = __builtin_amdgcn_mfma_f32_16x16x32_bf16(a[0][c], bf, acc0, 0, 0, 0);
      acc1 = __builtin_amdgcn_mfma_f32_16x16x32_bf16(a[1][c], bf, acc1, 0, 0, 0);
    }
#pragma unroll
    for (int r = 0; r < 4; r++) {
      float v0 = fmaf(m2w, acc0[r], fmaf(wt, sr[0][r], bb));
      float v1 = fmaf(m2w, acc1[r], fmaf(wt, sr[1][r], bb));
      unsigned u0 = (__builtin_bit_cast(unsigned, v0) & 0xFFFFFE00u) | code;
      unsigned u1 = (__builtin_bit_cast(unsigned, v1) & 0xFFFFFE00u) | code;
      pmin[0][r] = min(pmin[0][r], u0);
      pmin[1][r] = min(pmin[1][r], u1);
    }
  }

  // --- Butterfly min across the 16 lanes of each group (1 shfl + 1 min/step).
#pragma unroll
  for (int m = 1; m <= 8; m <<= 1) {
#pragma unroll
    for (int rg = 0; rg < 2; rg++)
#pragma unroll
      for (int r = 0; r < 4; r++) {
        unsigned o = (unsigned)__shfl_xor((int)pmin[rg][r], m);
        pmin[rg][r] = min(pmin[rg][r], o);
      }
  }

  // --- T14 store: issue first 8 gathers, do loss/idx bookkeeping under their
  // latency, then write; repeat for the second 8.
  const uint4* __restrict__ esrc = (const uint4*)emb32;   // 32 uint4/row
  uint4* __restrict__ outu = (uint4*)out_q + rowbase * 32;
  const int col = lane & 31;
  const int hi = lane >> 5;                 // 0: row 2it, 1: row 2it+1
  int scode[16];
#pragma unroll
  for (int it = 0; it < 16; it++) {
    const int row0 = 2 * it;                // compile-time
    const int rg = row0 >> 4;
    const int gn = (row0 >> 2) & 3;
    const int r0 = row0 & 3;                // even
    int c0 = __shfl((int)pmin[rg][r0], gn * 16);
    int c1 = __shfl((int)pmin[rg][r0 + 1], gn * 16);
    scode[it] = (hi ? c1 : c0) & 511;
  }

  uint4 vbuf[8];
#pragma unroll
  for (int j = 0; j < 8; j++)
    vbuf[j] = esrc[scode[j] * 32 + col];    // in flight...

  // ...bookkeeping under gather latency: indices out + per-wave loss partial.
  {
    float l0 = 0.f;
#pragma unroll
    for (int rg = 0; rg < 2; rg++)
#pragma unroll
      for (int r = 0; r < 4; r++) {
        unsigned wn = pmin[rg][r];
        int ci = (int)(wn & 511u);
        float dist = __builtin_bit_cast(float, wn & 0xFFFFFE00u);
        l0 = fmaf(dist, sm.wrcp[ci], l0);
        if (lr == 0) out_idx[rowbase + rg * 16 + g * 4 + r] = (float)ci;
      }
    l0 += __shfl_xor(l0, 16);
    l0 += __shfl_xor(l0, 32);
    if (lane == 0) sm.lossp[wave] = l0;
  }

#pragma unroll
  for (int j = 0; j < 8; j++)
    outu[j * 64 + lane] = vbuf[j];
#pragma unroll
  for (int j = 0; j < 8; j++)
    vbuf[j] = esrc[scode[8 + j] * 32 + col];
#pragma unroll
  for (int j = 0; j < 8; j++)
    outu[(8 + j) * 64 + lane] = vbuf[j];

  // --- Per-block loss reduce + one atomic (256 atomics total).
  __syncthreads();
  if (wave == 0 && lane < NWAVES) {
    float s = sm.lossp[lane];
#pragma unroll
    for (int m = 1; m < NWAVES; m <<= 1) s += __shfl_xor(s, m);
    if (lane == 0) atomicAdd(out_loss, s * (1.6f / (float)QN));
  }
}

extern "C" void kernel_launch(void* const* d_in, const int* in_sizes, int n_in,
                              void* d_out, int out_size, void* d_ws, size_t ws_size,
                              hipStream_t stream) {
  const float* x = (const float*)d_in[0];
  const float* emb = (const float*)d_in[1];
  const float* scaling = (const float*)d_in[2];

  float* out_q = (float*)d_out;
  float* out_loss = out_q + QN;
  float* out_idx = out_q + QN + 1;

  unsigned short* emb_bf = (unsigned short*)d_ws;
  float* wv = (float*)((char*)d_ws + NCODES * DIM * 2);
  float* wse = wv + NCODES;
  float* wrcp = wse + NCODES;

  hipMemsetAsync(out_loss, 0, sizeof(float), stream);
  vq_prep<<<NCODES, 64, 0, stream>>>(emb, scaling, emb_bf, wv, wse, wrcp);
  vq_main<<<NBLOCKS, 1024, 0, stream>>>(x, emb, emb_bf, wv, wse, wrcp,
                                        out_q, out_idx, out_loss);
}

// Round 13
// 43.022 us; speedup vs baseline: 3.4874x; 1.1451x over previous
//
#include <hip/hip_runtime.h>

#define NCODES 512
#define DIM 128
#define NROWS (64*2048)          // 131072
#define QN (NROWS*DIM)           // 16777216
#define BLK_ROWS 256
#define NBLOCKS (NROWS/BLK_ROWS) // 512
#define NWAVES 8                 // 512 threads, 32 rows/wave

typedef __attribute__((ext_vector_type(4))) float f32x4;

#define GLOAD_LDS16(gp, lp) __builtin_amdgcn_global_load_lds( \
    (__attribute__((address_space(1))) void*)(gp), \
    (__attribute__((address_space(3))) void*)(lp), 16, 0, 0)

// ---------------- prep: fp8 codebook (frag-ordered, x512) + weights --------
// Codebook values ~U(+-1/512): scale by 512 into e4m3 normal range (exact
// pow2, folded back via m2w = -2w/512). Output layout is ALREADY the MFMA
// B-fragment order: slice (t,c) = 512B; lane l's 8B at slice+l*8 holds code
// t*16+(l&15), dims c*32+(l>>4)*8 .. +7. So vq_main stages LINEARLY.
__global__ void vq_prep(const float* __restrict__ emb, const float* __restrict__ scaling,
                        unsigned char* __restrict__ e8frag,
                        float* __restrict__ wv, float* __restrict__ wse,
                        float* __restrict__ wrcp) {
  int k = blockIdx.x;
  int l = threadIdx.x; // 64 lanes; dims d=2l, 2l+1
  float2 v = ((const float2*)(emb + k * DIM))[l];
  float ss = v.x * v.x + v.y * v.y;
#pragma unroll
  for (int m = 1; m < 64; m <<= 1) ss += __shfl_xor(ss, m);
  // fp8 pack of (512*e) pair -> low 2 bytes
  int p = __builtin_amdgcn_cvt_pk_fp8_f32(v.x * 512.0f, v.y * 512.0f, 0, false);
  int t = k >> 4, col = k & 15;
  int c = l >> 4, g = (l >> 2) & 3, jp = l & 3;
  // byte offset: ((t*4+c)*64 + g*16 + col)*8 + 2*jp
  *(unsigned short*)(e8frag + (((t * 4 + c) * 64 + g * 16 + col) << 3) + 2 * jp) =
      (unsigned short)(p & 0xFFFF);
  if (l == 0) {
    float hr = 40.0f + (float)k * (140.0f / 511.0f);
    float wt = 1.0f + scaling[k] * ((hr - 100.0f) * (1.0f / 70.0f));
    wv[k] = wt;
    wse[k] = wt * ss;        // w_k * ||e_k||^2 (exact f32)
    wrcp[k] = 1.0f / wt;
  }
}

// ---------------- main ----------------
// 512 blocks x 512 threads (8 waves x 32 rows). Full fp8 codebook (64KB) +
// tables = 71.7KB LDS -> 2 CO-RESIDENT blocks/CU (launch_bounds(512,4):
// 16 waves/CU, VGPR cap 128). Independent co-resident blocks overlap one
// block's HBM read/store with the other's LDS/MFMA sweep — no codebook split,
// no redundant x reads (R10 lesson). Sweep: ds_read_b64 (conflict-free) +
// mfma_f32_16x16x32_fp8_fp8 (bf16 rate), packed-u32 argmin (R8-validated),
// T14 store, per-block atomicAdd loss.
struct SmemT {
  unsigned char frag[NCODES * DIM]; // 65536 B fp8, fragment-ordered
  float w[NCODES];
  float wse[NCODES];
  float wrcp[NCODES];
  float lossp[NWAVES];
};

__global__ __launch_bounds__(512, 4) void vq_main(
    const float* __restrict__ x,
    const float* __restrict__ emb32,
    const unsigned char* __restrict__ e8frag,
    const float* __restrict__ wv,
    const float* __restrict__ wse,
    const float* __restrict__ wrcp,
    float* __restrict__ out_q,
    float* __restrict__ out_idx,
    float* __restrict__ out_loss) {
  __shared__ SmemT sm;
  const int tid = threadIdx.x;
  const int wave = tid >> 6, lane = tid & 63;
  const int g = lane >> 4, lr = lane & 15;
  const long rowbase = (long)blockIdx.x * BLK_ROWS + wave * 32;

  // --- Issue x loads (f32, registers) ---
  float4 xv[2][4][2];
#pragma unroll
  for (int rg = 0; rg < 2; rg++) {
    const float* xr = x + (rowbase + rg * 16 + lr) * DIM + g * 8;
#pragma unroll
    for (int c = 0; c < 4; c++) {
      xv[rg][c][0] = *(const float4*)(xr + c * 32);
      xv[rg][c][1] = *(const float4*)(xr + c * 32 + 4);
    }
  }

  // --- Stage fp8 codebook: LINEAR global_load_lds (prep pre-ordered it).
  {
#pragma unroll
    for (int i = 0; i < 8; i++) {
      int slot = i * 512 + tid;            // 16B slot 0..4095
      GLOAD_LDS16(e8frag + slot * 16, sm.frag + slot * 16);
    }
    sm.w[tid] = wv[tid]; sm.wse[tid] = wse[tid]; sm.wrcp[tid] = wrcp[tid];
    int t2 = tid + 512 - 512; (void)t2;
  }
  // second half of tables (512 threads, 512 codes -> exactly covered above)

  // --- Convert x to fp8 A fragments + row sumsq (f32-exact S).
  long a[2][4];
  float sr[2][4];
  {
    float srow[2];
#pragma unroll
    for (int rg = 0; rg < 2; rg++) {
      float ss = 0.f;
#pragma unroll
      for (int c = 0; c < 4; c++) {
        float4 v0 = xv[rg][c][0];
        float4 v1 = xv[rg][c][1];
        ss += v0.x * v0.x + v0.y * v0.y + v0.z * v0.z + v0.w * v0.w;
        ss += v1.x * v1.x + v1.y * v1.y + v1.z * v1.z + v1.w * v1.w;
        int lo = __builtin_amdgcn_cvt_pk_fp8_f32(v0.x, v0.y, 0, false);
        lo = __builtin_amdgcn_cvt_pk_fp8_f32(v0.z, v0.w, lo, true);
        int hi = __builtin_amdgcn_cvt_pk_fp8_f32(v1.x, v1.y, 0, false);
        hi = __builtin_amdgcn_cvt_pk_fp8_f32(v1.z, v1.w, hi, true);
        a[rg][c] = (long)(((unsigned long long)(unsigned)hi << 32) |
                          (unsigned long long)(unsigned)lo);
      }
      ss += __shfl_xor(ss, 16);
      ss += __shfl_xor(ss, 32);
      srow[rg] = ss;
    }
#pragma unroll
    for (int rg = 0; rg < 2; rg++)
#pragma unroll
      for (int r = 0; r < 4; r++)
        sr[rg][r] = __shfl(srow[rg], g * 4 + r);  // ||x||^2 of C-row 4g+r
  }
  __syncthreads();  // codebook staged; LDS read-only until loss phase

  // --- Sweep 32 column tiles of 16 codes; packed-u32 running argmin.
  unsigned pmin[2][4];
#pragma unroll
  for (int rg = 0; rg < 2; rg++)
#pragma unroll
    for (int r = 0; r < 4; r++) pmin[rg][r] = 0xFFFFFFFFu;

  const long* __restrict__ bbase = (const long*)sm.frag + lane;
#pragma unroll 2
  for (int t = 0; t < 32; t++) {
    const unsigned code = t * 16 + lr;    // B col = lane&15
    const float wt = sm.w[code];
    const float bb = sm.wse[code];
    const float m2w = -2.0f * wt * (1.0f / 512.0f);  // undo codebook x512
    f32x4 acc0 = {0.f, 0.f, 0.f, 0.f};
    f32x4 acc1 = {0.f, 0.f, 0.f, 0.f};
#pragma unroll
    for (int c = 0; c < 4; c++) {
      long bf = bbase[(t * 4 + c) * 64];
      acc0 = __builtin_amdgcn_mfma_f32_16x16x32_fp8_fp8(a[0][c], bf, acc0, 0, 0, 0);
      acc1 = __builtin_amdgcn_mfma_f32_16x16x32_fp8_fp8(a[1][c], bf, acc1, 0, 0, 0);
    }
#pragma unroll
    for (int r = 0; r < 4; r++) {
      float v0 = fmaf(m2w, acc0[r], fmaf(wt, sr[0][r], bb));
      float v1 = fmaf(m2w, acc1[r], fmaf(wt, sr[1][r], bb));
      unsigned u0 = (__builtin_bit_cast(unsigned, v0) & 0xFFFFFE00u) | code;
      unsigned u1 = (__builtin_bit_cast(unsigned, v1) & 0xFFFFFE00u) | code;
      pmin[0][r] = min(pmin[0][r], u0);
      pmin[1][r] = min(pmin[1][r], u1);
    }
  }

  // --- Butterfly min across the 16 lanes of each group.
#pragma unroll
  for (int m = 1; m <= 8; m <<= 1) {
#pragma unroll
    for (int rg = 0; rg < 2; rg++)
#pragma unroll
      for (int r = 0; r < 4; r++) {
        unsigned o = (unsigned)__shfl_xor((int)pmin[rg][r], m);
        pmin[rg][r] = min(pmin[rg][r], o);
      }
  }

  // --- T14 store: issue 8 gathers, bookkeeping under latency, write; repeat.
  const uint4* __restrict__ esrc = (const uint4*)emb32;   // 32 uint4/row
  uint4* __restrict__ outu = (uint4*)out_q + rowbase * 32;
  const int col = lane & 31;
  const int hi2 = lane >> 5;                // 0: row 2it, 1: row 2it+1
  int scode[16];
#pragma unroll
  for (int it = 0; it < 16; it++) {
    const int row0 = 2 * it;                // compile-time
    const int rg = row0 >> 4;
    const int gn = (row0 >> 2) & 3;
    const int r0 = row0 & 3;                // even
    int c0 = __shfl((int)pmin[rg][r0], gn * 16);
    int c1 = __shfl((int)pmin[rg][r0 + 1], gn * 16);
    scode[it] = (hi2 ? c1 : c0) & 511;
  }

  uint4 vbuf[8];
#pragma unroll
  for (int j = 0; j < 8; j++)
    vbuf[j] = esrc[scode[j] * 32 + col];    // in flight...

  // ...bookkeeping under gather latency: indices + per-wave loss partial.
  {
    float l0 = 0.f;
#pragma unroll
    for (int rg = 0; rg < 2; rg++)
#pragma unroll
      for (int r = 0; r < 4; r++) {
        unsigned wn = pmin[rg][r];
        int ci = (int)(wn & 511u);
        float dist = __builtin_bit_cast(float, wn & 0xFFFFFE00u);
        l0 = fmaf(dist, sm.wrcp[ci], l0);
        if (lr == 0) out_idx[rowbase + rg * 16 + g * 4 + r] = (float)ci;
      }
    l0 += __shfl_xor(l0, 16);
    l0 += __shfl_xor(l0, 32);
    if (lane == 0) sm.lossp[wave] = l0;
  }

#pragma unroll
  for (int j = 0; j < 8; j++)
    outu[j * 64 + lane] = vbuf[j];
#pragma unroll
  for (int j = 0; j < 8; j++)
    vbuf[j] = esrc[scode[8 + j] * 32 + col];
#pragma unroll
  for (int j = 0; j < 8; j++)
    outu[(8 + j) * 64 + lane] = vbuf[j];

  // --- Per-block loss reduce + one atomic (512 atomics total).
  __syncthreads();
  if (wave == 0 && lane < NWAVES) {
    float s = sm.lossp[lane];
#pragma unroll
    for (int m = 1; m < NWAVES; m <<= 1) s += __shfl_xor(s, m);
    if (lane == 0) atomicAdd(out_loss, s * (1.6f / (float)QN));
  }
}

extern "C" void kernel_launch(void* const* d_in, const int* in_sizes, int n_in,
                              void* d_out, int out_size, void* d_ws, size_t ws_size,
                              hipStream_t stream) {
  const float* x = (const float*)d_in[0];
  const float* emb = (const float*)d_in[1];
  const float* scaling = (const float*)d_in[2];

  float* out_q = (float*)d_out;
  float* out_loss = out_q + QN;
  float* out_idx = out_q + QN + 1;

  unsigned char* e8frag = (unsigned char*)d_ws;                   // 64KB
  float* wv = (float*)((char*)d_ws + NCODES * DIM);               // 2KB
  float* wse = wv + NCODES;                                       // 2KB
  float* wrcp = wse + NCODES;                                     // 2KB

  hipMemsetAsync(out_loss, 0, sizeof(float), stream);
  vq_prep<<<NCODES, 64, 0, stream>>>(emb, scaling, e8frag, wv, wse, wrcp);
  vq_main<<<NBLOCKS, 512, 0, stream>>>(x, emb, e8frag, wv, wse, wrcp,
                                       out_q, out_idx, out_loss);
}